// Round 7
// baseline (595.797 us; speedup 1.0000x reference)
//
#include <hip/hip_runtime.h>
#include <hip/hip_fp16.h>
#include <math.h>

#define N_NODES 50000
#define T_STEPS 8
#define E_EDGES 800000
#define XD 128
#define HD 64
#define ZD 32
#define M_TOT (T_STEPS * N_NODES)   // 400000
#define TE_TOT (T_STEPS * E_EDGES)  // 6400000

#define NBKT 196                    // ceil(50000/256) buckets of 256 dst values
#define BPT 125                     // pass-A blocks per timestep
#define EPB 6400                    // edges per pass-A block (125*6400 = 800000)
#define NBLK_A (T_STEPS * BPT)      // 1000
#define CNTA_LEN (T_STEPS * NBKT * BPT)  // 196000
#define NBUCK_T (T_STEPS * NBKT)    // 1568

#define SCAN_CH 2048
#define SCANA_NB ((CNTA_LEN + SCAN_CH - 1) / SCAN_CH)  // 96

__device__ __forceinline__ float4 h4tof4(ushort4 u) {
  return make_float4(__half2float(__ushort_as_half(u.x)),
                     __half2float(__ushort_as_half(u.y)),
                     __half2float(__ushort_as_half(u.z)),
                     __half2float(__ushort_as_half(u.w)));
}
__device__ __forceinline__ float cnorm(unsigned int c) {
  return __half2float(__ushort_as_half((unsigned short)(c >> 16)));
}

// ---------------- h0 = x @ W1  ([N,128] x [128,64]) -> fp16 ----------------
__global__ __launch_bounds__(256) void k_h0(const float* __restrict__ x,
                                            const float* __restrict__ W1,
                                            unsigned short* __restrict__ h0h) {
  __shared__ float xs[256 * 33];
  __shared__ float w1s[32 * 64];
  const int tid = threadIdx.x;
  const int nb = blockIdx.x * 256;
  const int nl_base = tid & 63;
  const int jg = tid >> 6;
  const float4* x4 = (const float4*)x;
  const float4* W14 = (const float4*)W1;

  float acc[4][16];
#pragma unroll
  for (int i = 0; i < 4; ++i)
#pragma unroll
    for (int j = 0; j < 16; ++j) acc[i][j] = 0.f;

  for (int kc = 0; kc < 4; ++kc) {
#pragma unroll
    for (int r = 0; r < 8; ++r) {
      int f4 = tid + r * 256;
      int nl = f4 >> 3;
      int k4 = f4 & 7;
      float4 v = make_float4(0.f, 0.f, 0.f, 0.f);
      int node = nb + nl;
      if (node < N_NODES) v = x4[node * 32 + kc * 8 + k4];
      int base = nl * 33 + k4 * 4;
      xs[base + 0] = v.x; xs[base + 1] = v.y;
      xs[base + 2] = v.z; xs[base + 3] = v.w;
    }
#pragma unroll
    for (int r = 0; r < 2; ++r) {
      int f4 = tid + r * 256;
      ((float4*)w1s)[f4] = W14[kc * 512 + f4];
    }
    __syncthreads();
#pragma unroll 4
    for (int k = 0; k < 32; ++k) {
      float xv[4];
#pragma unroll
      for (int i = 0; i < 4; ++i) xv[i] = xs[(nl_base + i * 64) * 33 + k];
      const float* wr = &w1s[k * 64 + jg * 16];
      float4 w0 = *(const float4*)(wr + 0);
      float4 w1v = *(const float4*)(wr + 4);
      float4 w2v = *(const float4*)(wr + 8);
      float4 w3v = *(const float4*)(wr + 12);
#pragma unroll
      for (int i = 0; i < 4; ++i) {
        acc[i][0] += xv[i] * w0.x;  acc[i][1] += xv[i] * w0.y;
        acc[i][2] += xv[i] * w0.z;  acc[i][3] += xv[i] * w0.w;
        acc[i][4] += xv[i] * w1v.x; acc[i][5] += xv[i] * w1v.y;
        acc[i][6] += xv[i] * w1v.z; acc[i][7] += xv[i] * w1v.w;
        acc[i][8] += xv[i] * w2v.x; acc[i][9] += xv[i] * w2v.y;
        acc[i][10] += xv[i] * w2v.z; acc[i][11] += xv[i] * w2v.w;
        acc[i][12] += xv[i] * w3v.x; acc[i][13] += xv[i] * w3v.y;
        acc[i][14] += xv[i] * w3v.z; acc[i][15] += xv[i] * w3v.w;
      }
    }
    __syncthreads();
  }
  ushort4* h4p = (ushort4*)h0h;
#pragma unroll
  for (int i = 0; i < 4; ++i) {
    int node = nb + nl_base + i * 64;
    if (node < N_NODES) {
#pragma unroll
      for (int q = 0; q < 4; ++q) {
        ushort4 s;
        s.x = __half_as_ushort(__float2half(acc[i][q * 4 + 0]));
        s.y = __half_as_ushort(__float2half(acc[i][q * 4 + 1]));
        s.z = __half_as_ushort(__float2half(acc[i][q * 4 + 2]));
        s.w = __half_as_ushort(__float2half(acc[i][q * 4 + 3]));
        h4p[(size_t)node * 16 + jg * 4 + q] = s;
      }
    }
  }
}

// ---------------- pass A: per-block LDS histogram over dst>>8 ----------------
__global__ __launch_bounds__(256) void k_binhist(const int* __restrict__ ei,
                                                 unsigned short* __restrict__ rankA,
                                                 unsigned int* __restrict__ cntA) {
  __shared__ unsigned int hist[NBKT];
  const int tid = threadIdx.x, bid = blockIdx.x;
  const int t = bid / BPT, b = bid - t * BPT;
  if (tid < NBKT) hist[tid] = 0;
  __syncthreads();
  const int* dstp = ei + (t * 2 + 1) * E_EDGES + b * EPB;
  const int gbase = t * E_EDGES + b * EPB;
#pragma unroll
  for (int it = 0; it < EPB / 256; ++it) {
    int e = it * 256 + tid;
    int dst = dstp[e];
    unsigned int r = atomicAdd(&hist[dst >> 8], 1u);
    rankA[gbase + e] = (unsigned short)r;
  }
  __syncthreads();
  if (tid < NBKT) cntA[(t * NBKT + tid) * BPT + b] = hist[tid];
}

// ---------------- hierarchical exclusive scan over cntA ----------------
__global__ __launch_bounds__(256) void k_scan1(const unsigned int* __restrict__ cntA,
                                               int* __restrict__ bsum) {
  __shared__ int s[256];
  int bid = blockIdx.x, tid = threadIdx.x;
  int base = bid * SCAN_CH;
  int v = 0;
#pragma unroll
  for (int r = 0; r < 8; ++r) {
    int i = base + tid + r * 256;
    if (i < CNTA_LEN) v += (int)cntA[i];
  }
  s[tid] = v;
  __syncthreads();
  for (int off = 128; off > 0; off >>= 1) {
    if (tid < off) s[tid] += s[tid + off];
    __syncthreads();
  }
  if (tid == 0) bsum[bid] = s[0];
}

__global__ __launch_bounds__(256) void k_scan2(const int* __restrict__ bsum,
                                               int* __restrict__ bpre) {
  __shared__ int s[256];
  int tid = threadIdx.x;
  int v = (tid < SCANA_NB) ? bsum[tid] : 0;
  s[tid] = v;
  __syncthreads();
  for (int off = 1; off < 256; off <<= 1) {
    int t = (tid >= off) ? s[tid - off] : 0;
    __syncthreads();
    s[tid] += t;
    __syncthreads();
  }
  bpre[tid] = s[tid] - v;
}

__global__ __launch_bounds__(256) void k_scan3(const unsigned int* __restrict__ cntA,
                                               const int* __restrict__ bpre,
                                               unsigned int* __restrict__ scannedA) {
  __shared__ int s[256];
  int bid = blockIdx.x, tid = threadIdx.x;
  int i0 = bid * SCAN_CH + tid * 8;
  int c[8];
  int lsum = 0;
#pragma unroll
  for (int j = 0; j < 8; ++j) {
    int i = i0 + j;
    c[j] = (i < CNTA_LEN) ? (int)cntA[i] : 0;
    lsum += c[j];
  }
  int v = lsum;
  s[tid] = v;
  __syncthreads();
  for (int off = 1; off < 256; off <<= 1) {
    int t = (tid >= off) ? s[tid - off] : 0;
    __syncthreads();
    s[tid] += t;
    __syncthreads();
  }
  int run = bpre[bid] + (s[tid] - v);
#pragma unroll
  for (int j = 0; j < 8; ++j) {
    int i = i0 + j;
    if (i < CNTA_LEN) {
      scannedA[i] = (unsigned int)run;
      run += c[j];
    }
  }
}

// ---------------- pass A scatter into bucket-grouped buffer ----------------
__global__ __launch_bounds__(256) void k_binscatter(const int* __restrict__ ei,
                                                    const float* __restrict__ ew,
                                                    const unsigned short* __restrict__ rankA,
                                                    const unsigned int* __restrict__ scannedA,
                                                    uint2* __restrict__ ebuf) {
  int i = blockIdx.x * 256 + threadIdx.x;
  int t = i / E_EDGES;
  int e = i - t * E_EDGES;
  int b = e / EPB;
  int src = ei[t * 2 * E_EDGES + e];
  int dst = ei[(t * 2 + 1) * E_EDGES + e];
  float w = ew[i];
  int bkt = dst >> 8;
  unsigned int pos = scannedA[(t * NBKT + bkt) * BPT + b] + rankA[i];
  ebuf[pos] = make_uint2(((unsigned int)(dst & 255) << 16) | (unsigned int)src,
                         __float_as_uint(w));
}

// ---------------- pass B1: per-bucket cnt+deg, dinv, row_off ----------------
__global__ __launch_bounds__(256) void k_bucket1(const uint2* __restrict__ ebuf,
                                                 const unsigned int* __restrict__ scannedA,
                                                 unsigned int* __restrict__ localscan,
                                                 float* __restrict__ dinv,
                                                 int* __restrict__ row_off) {
  __shared__ unsigned int cnt[256];
  __shared__ float degs[256];
  __shared__ unsigned int sc[256];
  const int tid = threadIdx.x, blk = blockIdx.x;
  const int t = blk / NBKT, bkt = blk - t * NBKT;
  const unsigned int base = scannedA[blk * BPT];
  const unsigned int end = (blk == NBUCK_T - 1) ? (unsigned int)TE_TOT
                                                : scannedA[(blk + 1) * BPT];
  cnt[tid] = 0;
  degs[tid] = 0.f;
  __syncthreads();
  for (unsigned int i = base + tid; i < end; i += 256) {
    uint2 v = ebuf[i];
    unsigned int dlo = v.x >> 16;
    atomicAdd(&cnt[dlo], 1u);
    atomicAdd(&degs[dlo], __uint_as_float(v.y));
  }
  __syncthreads();
  unsigned int myc = cnt[tid];
  sc[tid] = myc;
  __syncthreads();
  for (int off = 1; off < 256; off <<= 1) {
    unsigned int a = (tid >= off) ? sc[tid - off] : 0;
    __syncthreads();
    sc[tid] += a;
    __syncthreads();
  }
  unsigned int start = base + (sc[tid] - myc);
  localscan[blk * 256 + tid] = start;
  int dst = bkt * 256 + tid;
  if (dst < N_NODES) {
    int tn = t * N_NODES + dst;
    dinv[tn] = rsqrtf(1.0f + degs[tid]);
    row_off[tn] = (int)start;
  }
  if (blk == NBUCK_T - 1 && tid == 0) row_off[M_TOT] = TE_TOT;
}

// ------ pass B2: regroup to final packed u32 CSR (src | half(w*dinv_src)<<16) ------
// No LDS staging (csr32 is a separate buffer now) — direct coalesced read.
__global__ __launch_bounds__(256) void k_bucket2(const uint2* __restrict__ ebuf,
                                                 const unsigned int* __restrict__ scannedA,
                                                 const unsigned int* __restrict__ localscan,
                                                 const float* __restrict__ dinv,
                                                 unsigned int* __restrict__ csr32) {
  __shared__ unsigned int cursor[256];
  const int tid = threadIdx.x, blk = blockIdx.x;
  const int t = blk / NBKT;
  const unsigned int base = scannedA[blk * BPT];
  const unsigned int end = (blk == NBUCK_T - 1) ? (unsigned int)TE_TOT
                                                : scannedA[(blk + 1) * BPT];
  cursor[tid] = localscan[blk * 256 + tid];
  __syncthreads();
  const float* dv = dinv + t * N_NODES;
  for (unsigned int i = base + tid; i < end; i += 256) {
    uint2 v = ebuf[i];
    unsigned int dlo = v.x >> 16;
    unsigned int src = v.x & 0xFFFFu;
    unsigned int slot = atomicAdd(&cursor[dlo], 1u);
    float norm = __uint_as_float(v.y) * dv[src];
    csr32[slot] = src | ((unsigned int)__half_as_ushort(__float2half(norm)) << 16);
  }
}

// ---------------- layer-1 gather (fp16 h0) + ReLU + fused h1@W2 -> fp16 g ------
// Predicated quad pipeline: loads for quad i+1 in flight while FMA-ing quad i.
__global__ __launch_bounds__(256) void k_gather1(
    const unsigned short* __restrict__ h0h, const float* __restrict__ dinv,
    const int* __restrict__ row_off, const unsigned int* __restrict__ csr,
    const float* __restrict__ W2, const float* __restrict__ b1,
    unsigned short* __restrict__ g16) {
  __shared__ float h1s[16 * 65];
  __shared__ float w2s[64 * 32];
  const int tid = threadIdx.x;
#pragma unroll
  for (int r = 0; r < 2; ++r)
    ((float4*)w2s)[tid + r * 256] = ((const float4*)W2)[tid + r * 256];

  const int grp = tid >> 4;
  const unsigned lane = tid & 15;
  const int tn = blockIdx.x * 16 + grp;
  const int t = tn / N_NODES;
  const int n = tn - t * N_NODES;
  const float dvn = dinv[tn];
  const ushort4* h4 = (const ushort4*)h0h;
  float4 bv = ((const float4*)b1)[lane];

  float4 acc = h4tof4(h4[(unsigned)n * 16u + lane]);
  acc.x *= dvn; acc.y *= dvn; acc.z *= dvn; acc.w *= dvn;

  const int e0 = row_off[tn], e1 = row_off[tn + 1];
  const int e1m1 = e1 - 1;
  const int nq = (e1 - e0 + 3) >> 2;

  float nA[4], nB[4];
  ushort4 uA[4], uB[4];

  // clamped predicated quad load (OOB-clamp reads stay inside d_ws interior)
#define LOADQ1(qe, nn, uu)                                        \
  {                                                               \
    _Pragma("unroll") for (int k_ = 0; k_ < 4; ++k_) {            \
      int ee = (qe) + k_;                                         \
      unsigned cc = csr[ee < e1m1 ? ee : e1m1];                   \
      nn[k_] = (ee < e1) ? cnorm(cc) : 0.f;                       \
      uu[k_] = h4[(cc & 0xFFFFu) * 16u + lane];                   \
    }                                                             \
  }
#define FMAQ1(nn, uu)                                             \
  {                                                               \
    _Pragma("unroll") for (int k_ = 0; k_ < 4; ++k_) {            \
      float4 f = h4tof4(uu[k_]);                                  \
      acc.x += nn[k_] * f.x; acc.y += nn[k_] * f.y;               \
      acc.z += nn[k_] * f.z; acc.w += nn[k_] * f.w;               \
    }                                                             \
  }

  int q = 0;
  if (nq > 0) LOADQ1(e0, nA, uA);
  while (q + 2 <= nq) {
    LOADQ1(e0 + (q + 1) * 4, nB, uB);
    FMAQ1(nA, uA);
    if (q + 3 <= nq) LOADQ1(e0 + (q + 2) * 4, nA, uA);
    FMAQ1(nB, uB);
    q += 2;
  }
  if (q < nq) FMAQ1(nA, uA);

  int hb = grp * 65 + (int)lane * 4;
  h1s[hb + 0] = fmaxf(acc.x * dvn + bv.x, 0.f);
  h1s[hb + 1] = fmaxf(acc.y * dvn + bv.y, 0.f);
  h1s[hb + 2] = fmaxf(acc.z * dvn + bv.z, 0.f);
  h1s[hb + 3] = fmaxf(acc.w * dvn + bv.w, 0.f);
  __syncthreads();

  const int n1i = tid >> 5;
  const int j = tid & 31;
  float a0 = 0.f, a1 = 0.f;
#pragma unroll 8
  for (int k = 0; k < 64; ++k) {
    float wv = w2s[k * 32 + j];
    a0 += h1s[n1i * 65 + k] * wv;
    a1 += h1s[(n1i + 8) * 65 + k] * wv;
  }
  const int tnb = blockIdx.x * 16;
  g16[(size_t)(tnb + n1i) * 32 + j] = __half_as_ushort(__float2half(a0));
  g16[(size_t)(tnb + n1i + 8) * 32 + j] = __half_as_ushort(__float2half(a1));
}

// ---------------- layer-2 gather (fp16 g) + bias + tanh -> out ----------------
__global__ __launch_bounds__(256) void k_gather2(
    const unsigned short* __restrict__ g16, const float* __restrict__ dinv,
    const int* __restrict__ row_off, const unsigned int* __restrict__ csr,
    const float* __restrict__ b2, float* __restrict__ out) {
  // bijective XCD-chunked swizzle (nwg=12500: q=1562, r=4)
  const int nwg = gridDim.x;
  const int orig = blockIdx.x;
  const int xcd = orig & 7, lid = orig >> 3;
  const int qq = nwg >> 3, rr = nwg & 7;
  const int bid = (xcd < rr ? xcd * (qq + 1) : rr * (qq + 1) + (xcd - rr) * qq) + lid;

  const int tid = threadIdx.x;
  const int grp = tid >> 3;
  const unsigned lane = tid & 7;
  const int tn = bid * 32 + grp;
  const int t = tn / N_NODES;
  const unsigned tbase = (unsigned)(t * N_NODES);
  const float dvn = dinv[tn];
  const ushort4* g4 = (const ushort4*)g16;
  float4 bv = ((const float4*)b2)[lane];

  float4 acc = h4tof4(g4[(unsigned)tn * 8u + lane]);
  acc.x *= dvn; acc.y *= dvn; acc.z *= dvn; acc.w *= dvn;

  const int e0 = row_off[tn], e1 = row_off[tn + 1];
  const int e1m1 = e1 - 1;
  const int nq = (e1 - e0 + 3) >> 2;

  float nA[4], nB[4];
  ushort4 uA[4], uB[4];

#define LOADQ2(qe, nn, uu)                                        \
  {                                                               \
    _Pragma("unroll") for (int k_ = 0; k_ < 4; ++k_) {            \
      int ee = (qe) + k_;                                         \
      unsigned cc = csr[ee < e1m1 ? ee : e1m1];                   \
      nn[k_] = (ee < e1) ? cnorm(cc) : 0.f;                       \
      uu[k_] = g4[(tbase + (cc & 0xFFFFu)) * 8u + lane];          \
    }                                                             \
  }

  int q = 0;
  if (nq > 0) LOADQ2(e0, nA, uA);
  while (q + 2 <= nq) {
    LOADQ2(e0 + (q + 1) * 4, nB, uB);
    FMAQ1(nA, uA);
    if (q + 3 <= nq) LOADQ2(e0 + (q + 2) * 4, nA, uA);
    FMAQ1(nB, uB);
    q += 2;
  }
  if (q < nq) FMAQ1(nA, uA);

  float4 z;
  z.x = tanhf(acc.x * dvn + bv.x);
  z.y = tanhf(acc.y * dvn + bv.y);
  z.z = tanhf(acc.z * dvn + bv.z);
  z.w = tanhf(acc.w * dvn + bv.w);
  ((float4*)out)[(size_t)tn * 8 + lane] = z;
}

extern "C" void kernel_launch(void* const* d_in, const int* in_sizes, int n_in,
                              void* d_out, int out_size, void* d_ws, size_t ws_size,
                              hipStream_t stream) {
  const float* x = (const float*)d_in[0];
  const int* ei = (const int*)d_in[1];
  const float* ew = (const float*)d_in[2];
  const float* W1 = (const float*)d_in[3];
  const float* b1 = (const float*)d_in[4];
  const float* W2 = (const float*)d_in[5];
  const float* b2 = (const float*)d_in[6];
  float* out = (float*)d_out;

  char* base = (char*)d_ws;
  size_t o = 0;
  auto alloc = [&](size_t bytes) -> char* {
    char* r = base + o;
    o = (o + bytes + 255) & ~(size_t)255;
    return r;
  };
  // Order matters: clamped OOB reads from gather kernels (h4 <= +2MB past h0h,
  // csr32[-1], g4 <= +1MB past g16) must land INSIDE d_ws. ebuf goes last as a
  // 51MB interior cushion is not needed there; g16/csr32 are mid-buffer.
  unsigned short* h0h = (unsigned short*)alloc((size_t)N_NODES * HD * 2);   // 6.4 MB
  float* dinv = (float*)alloc((size_t)M_TOT * 4);                           // 1.6 MB
  int* row_off = (int*)alloc((size_t)(M_TOT + 1) * 4);                      // 1.6 MB
  unsigned int* localscan = (unsigned int*)alloc((size_t)NBUCK_T * 256 * 4);// 1.6 MB
  unsigned int* cntA = (unsigned int*)alloc((size_t)CNTA_LEN * 4);          // 0.78 MB
  unsigned int* scannedA = (unsigned int*)alloc((size_t)CNTA_LEN * 4);
  int* bsum = (int*)alloc(1024);
  int* bpre = (int*)alloc(1024);
  unsigned short* g16 = (unsigned short*)alloc((size_t)M_TOT * ZD * 2);     // 25.6 MB
  unsigned int* csr32 = (unsigned int*)alloc((size_t)TE_TOT * 4);           // 25.6 MB
  uint2* ebuf = (uint2*)alloc((size_t)TE_TOT * 8);                          // 51.2 MB (last)
  // rankA aliases g16: dead after k_binscatter, before k_gather1 writes g16
  unsigned short* rankA = (unsigned short*)g16;                             // 12.8 MB
  // total ~115 MB; no memsets needed (everything fully written before read)

  k_h0<<<(N_NODES + 255) / 256, 256, 0, stream>>>(x, W1, h0h);
  k_binhist<<<NBLK_A, 256, 0, stream>>>(ei, rankA, cntA);
  k_scan1<<<SCANA_NB, 256, 0, stream>>>(cntA, bsum);
  k_scan2<<<1, 256, 0, stream>>>(bsum, bpre);
  k_scan3<<<SCANA_NB, 256, 0, stream>>>(cntA, bpre, scannedA);
  k_binscatter<<<TE_TOT / 256, 256, 0, stream>>>(ei, ew, rankA, scannedA, ebuf);
  k_bucket1<<<NBUCK_T, 256, 0, stream>>>(ebuf, scannedA, localscan, dinv, row_off);
  k_bucket2<<<NBUCK_T, 256, 0, stream>>>(ebuf, scannedA, localscan, dinv, csr32);
  k_gather1<<<M_TOT / 16, 256, 0, stream>>>(h0h, dinv, row_off, csr32, W2, b1, g16);
  k_gather2<<<M_TOT / 32, 256, 0, stream>>>(g16, dinv, row_off, csr32, b2, out);
}